// Round 2
// baseline (822.731 us; speedup 1.0000x reference)
//
#include <hip/hip_runtime.h>
#include <hip/hip_bf16.h>
#include <cstdint>

// BahdanauAttention on MI355X.
// Pipeline (all on `stream`):
//  1) memset scores region (d_out attn area) = 0
//  2) wt_k:      W_enc (W_attn rows 1024..2047) -> transposed bf16 Wt[n][k] in ws (2 MB)
//  3) dec_proj_k: dp[b][n] = dec_hidden @ W_dec + b_attn  -> parked in d_out context region
//  4) gemm_scores: bf16 MFMA 16x16x32, 128x128x64 tiles, XOR-swizzled LDS,
//                  fused epilogue: scores[m] += sum_n tanh(C+dp)*v_w  (atomicAdd)
//  5) softmax_k:  in-place masked softmax over scores -> attn weights (final output region)
//  6) memset context region = 0
//  7) context_k:  context[b][e] = sum_s attn * enc (fp32, atomicAdd partials over s-chunks)

#define ENCD 1024
#define DECD 1024
#define BATCH 32
#define SEQ 2048
#define MTOT (BATCH * SEQ)  // 65536
#define KDIM 1024
#define NDIM 1024

typedef __attribute__((ext_vector_type(4))) float f32x4;
typedef __attribute__((ext_vector_type(8))) __bf16 bf16x8;   // mfma operand type (LLVM 'V8y')
typedef __attribute__((ext_vector_type(8))) unsigned short u16x8;

__device__ __forceinline__ unsigned short f2bf(float f) {
  unsigned int u = __builtin_bit_cast(unsigned int, f);
  u += 0x7fffu + ((u >> 16) & 1u);  // RNE
  return (unsigned short)(u >> 16);
}

// ---------------- W_enc transpose + bf16 convert: Wt[n][k] ----------------
__global__ void wt_k(const float* __restrict__ W, unsigned short* __restrict__ Wt) {
  __shared__ unsigned short t[64][65];
  const int k0 = blockIdx.x * 64, n0 = blockIdx.y * 64;
  const int tx = threadIdx.x & 63, ty = threadIdx.x >> 6;  // 64 x 4
#pragma unroll
  for (int i = 0; i < 16; ++i) {
    const int k = ty + i * 4;
    t[k][tx] = f2bf(W[(long)(DECD + k0 + k) * NDIM + n0 + tx]);  // coalesced along n
  }
  __syncthreads();
#pragma unroll
  for (int i = 0; i < 16; ++i) {
    const int n = ty + i * 4;
    Wt[(long)(n0 + n) * KDIM + k0 + tx] = t[tx][n];  // coalesced along k
  }
}

// ---------------- dec_proj + bias (fp32) ----------------
__global__ void dec_proj_k(const float* __restrict__ dec, const float* __restrict__ W,
                           const float* __restrict__ bias, float* __restrict__ dp) {
  const int idx = blockIdx.x * 256 + threadIdx.x;  // 32768 total
  const int b = idx >> 10;
  const int n = idx & 1023;
  const float* d = dec + b * DECD;
  float acc = bias[n];
  for (int k = 0; k < DECD; ++k)
    acc = fmaf(d[k], W[k * NDIM + n], acc);  // d[k] uniform per block, W coalesced
  dp[idx] = acc;
}

// ---------------- fused GEMM + tanh + v-dot -> scores ----------------
// C[m][n] = sum_k A[m][k] * Wt[n][k]; scores[m] += sum_n tanh(C+dp[b][n])*v[n]
__global__ __launch_bounds__(256, 2) void gemm_scores(
    const float* __restrict__ Ag, const unsigned short* __restrict__ Wt,
    const float* __restrict__ dp, const float* __restrict__ vw,
    float* __restrict__ scores) {
  __shared__ unsigned short sA[128 * 64];  // [row][k] bf16, chunks-of-8 XOR-swizzled
  __shared__ unsigned short sB[128 * 64];

  const int tid = threadIdx.x;
  const int lane = tid & 63;
  const int wave = tid >> 6;
  const int wm = wave >> 1, wn = wave & 1;   // 2x2 waves of 64x64
  const int quad = lane >> 4;
  const int l15 = lane & 15;

  const int bn = blockIdx.x;            // 0..7   (fastest: A-tile reuse in L2/L3)
  const int bm = blockIdx.y;            // 0..511
  const int n0 = bn * 128;
  const int row0 = bm * 128;
  const int bidx = bm >> 4;             // batch index (BM=128 divides S=2048)

  const int sr = tid >> 3;              // staging: row-in-32-group
  const int sc = tid & 7;               // staging: stored chunk slot

  const f32x4 zz = {0.f, 0.f, 0.f, 0.f};
  f32x4 acc[4][4];
#pragma unroll
  for (int i = 0; i < 4; ++i)
#pragma unroll
    for (int j = 0; j < 4; ++j) acc[i][j] = zz;

  for (int kt = 0; kt < 16; ++kt) {
    const int k0 = kt * 64;
    __syncthreads();  // protect LDS vs previous iter's reads
#pragma unroll
    for (int j = 0; j < 4; ++j) {
      const int r = sr + 32 * j;            // LDS-local row 0..127
      const int c = sc ^ (r & 7);           // global chunk stored at slot sc
      // A: fp32 -> bf16 convert in-register
      const float* src = Ag + (long)(row0 + r) * KDIM + (k0 + c * 8);
      f32x4 f0 = *(const f32x4*)src;
      f32x4 f1 = *(const f32x4*)(src + 4);
      u16x8 v;
      v[0] = f2bf(f0[0]); v[1] = f2bf(f0[1]); v[2] = f2bf(f0[2]); v[3] = f2bf(f0[3]);
      v[4] = f2bf(f1[0]); v[5] = f2bf(f1[1]); v[6] = f2bf(f1[2]); v[7] = f2bf(f1[3]);
      *(u16x8*)&sA[r * 64 + sc * 8] = v;
      // B: already bf16 (pre-transposed)
      const unsigned short* srcB = Wt + (long)(n0 + r) * KDIM + (k0 + c * 8);
      *(u16x8*)&sB[r * 64 + sc * 8] = *(const u16x8*)srcB;
    }
    __syncthreads();
#pragma unroll
    for (int h = 0; h < 2; ++h) {
      const int cs = ((h * 4 + quad) ^ (lane & 7)) * 8;  // swizzled chunk offset (ushorts)
      bf16x8 af[4], bf[4];
#pragma unroll
      for (int t = 0; t < 4; ++t) {
        af[t] = __builtin_bit_cast(bf16x8, *(const u16x8*)&sA[(wm * 64 + t * 16 + l15) * 64 + cs]);
        bf[t] = __builtin_bit_cast(bf16x8, *(const u16x8*)&sB[(wn * 64 + t * 16 + l15) * 64 + cs]);
      }
#pragma unroll
      for (int mt = 0; mt < 4; ++mt)
#pragma unroll
        for (int nt = 0; nt < 4; ++nt)
          acc[mt][nt] = __builtin_amdgcn_mfma_f32_16x16x32_bf16(
              af[mt], bf[nt], acc[mt][nt], 0, 0, 0);
    }
  }

  // Epilogue: e = tanh(C + dp[b][n]); partial = e * v[n]; reduce over n; atomicAdd
  float vv[4], dv[4];
#pragma unroll
  for (int nt = 0; nt < 4; ++nt) {
    const int n = n0 + wn * 64 + nt * 16 + l15;
    vv[nt] = vw[n];
    dv[nt] = dp[bidx * NDIM + n];
  }
#pragma unroll
  for (int mt = 0; mt < 4; ++mt) {
#pragma unroll
    for (int r = 0; r < 4; ++r) {
      float s = 0.f;
#pragma unroll
      for (int nt = 0; nt < 4; ++nt) {
        float x = acc[mt][nt][r] + dv[nt];
        x = fminf(fmaxf(x, -10.f), 10.f);
        const float e = __expf(2.f * x);                           // v_exp_f32
        s += (e - 1.f) * __builtin_amdgcn_rcpf(e + 1.f) * vv[nt];  // tanh
      }
      // sum across the 16 lanes holding cols of this row (xor 1,2,4,8 stays in l15-group)
      s += __shfl_xor(s, 1);
      s += __shfl_xor(s, 2);
      s += __shfl_xor(s, 4);
      s += __shfl_xor(s, 8);
      if (l15 == 0) {
        const int m = row0 + wm * 64 + mt * 16 + quad * 4 + r;  // C row = quad*4+reg
        atomicAdd(&scores[m], s);
      }
    }
  }
}

// ---------------- masked softmax, in-place on scores ----------------
__global__ void softmax_k(float* __restrict__ sc, const int* __restrict__ mask) {
  const int b = blockIdx.x;
  const int tid = threadIdx.x;
  const int w = tid >> 6;
  __shared__ float redm[4], reds[4];
  float* row = sc + b * SEQ;
  const int* mrow = mask + b * SEQ;
  float vals[8];
  float mx = -3.0e38f;
#pragma unroll
  for (int i = 0; i < 8; ++i) {
    const int s = tid + i * 256;
    float v = row[s];
    if (mrow[s] == 0) v = -1.0e9f;
    vals[i] = v;
    mx = fmaxf(mx, v);
  }
#pragma unroll
  for (int off = 1; off < 64; off <<= 1) mx = fmaxf(mx, __shfl_xor(mx, off));
  if ((tid & 63) == 0) redm[w] = mx;
  __syncthreads();
  mx = fmaxf(fmaxf(redm[0], redm[1]), fmaxf(redm[2], redm[3]));
  float sum = 0.f;
#pragma unroll
  for (int i = 0; i < 8; ++i) {
    vals[i] = __expf(vals[i] - mx);
    sum += vals[i];
  }
#pragma unroll
  for (int off = 1; off < 64; off <<= 1) sum += __shfl_xor(sum, off);
  if ((tid & 63) == 0) reds[w] = sum;
  __syncthreads();
  sum = reds[0] + reds[1] + reds[2] + reds[3];
  const float inv = 1.0f / sum;
#pragma unroll
  for (int i = 0; i < 8; ++i) row[tid + i * 256] = vals[i] * inv;
}

// ---------------- context = attn @ enc (fp32, memory-bound) ----------------
__global__ void context_k(const float* __restrict__ attn, const float* __restrict__ enc,
                          float* __restrict__ ctx) {
  const int b = blockIdx.y;          // 32
  const int s0 = blockIdx.x * 128;   // 16 s-chunks
  const int e = threadIdx.x * 4;     // 256 threads * float4 = 1024
  const float* arow = attn + b * SEQ + s0;
  const float* ebase = enc + (long)(b * SEQ + s0) * ENCD + e;
  f32x4 acc = {0.f, 0.f, 0.f, 0.f};
  for (int s = 0; s < 128; ++s) {
    const float w = arow[s];
    const f32x4 v = *(const f32x4*)(ebase + (long)s * ENCD);
    acc += w * v;
  }
  float* dst = ctx + b * ENCD + e;
  atomicAdd(dst + 0, acc[0]);
  atomicAdd(dst + 1, acc[1]);
  atomicAdd(dst + 2, acc[2]);
  atomicAdd(dst + 3, acc[3]);
}

extern "C" void kernel_launch(void* const* d_in, const int* in_sizes, int n_in,
                              void* d_out, int out_size, void* d_ws, size_t ws_size,
                              hipStream_t stream) {
  (void)in_sizes; (void)n_in; (void)out_size; (void)ws_size;
  const float* dec  = (const float*)d_in[0];
  const float* enc  = (const float*)d_in[1];
  const int*   mask = (const int*)d_in[2];
  const float* W    = (const float*)d_in[3];
  const float* bias = (const float*)d_in[4];
  const float* vw   = (const float*)d_in[5];

  float* ctx    = (float*)d_out;                   // context region: 32*1024
  float* scores = (float*)d_out + BATCH * ENCD;    // attn region: 32*2048 (scores in-place)
  unsigned short* Wt = (unsigned short*)d_ws;      // 1024*1024 bf16 = 2 MB

  hipMemsetAsync(scores, 0, (size_t)MTOT * sizeof(float), stream);
  wt_k<<<dim3(16, 16), 256, 0, stream>>>(W, Wt);
  dec_proj_k<<<128, 256, 0, stream>>>(dec, W, bias, ctx);      // dp parked in ctx region
  gemm_scores<<<dim3(8, 512), 256, 0, stream>>>(enc, Wt, ctx, vw, scores);
  softmax_k<<<32, 256, 0, stream>>>(scores, mask);
  hipMemsetAsync(ctx, 0, (size_t)(BATCH * ENCD) * sizeof(float), stream);
  context_k<<<dim3(16, 32), 256, 0, stream>>>(scores, enc, ctx);
}

// Round 3
// 609.687 us; speedup vs baseline: 1.3494x; 1.3494x over previous
//
#include <hip/hip_runtime.h>
#include <hip/hip_bf16.h>
#include <cstdint>

// BahdanauAttention on MI355X — round 3.
// Fast path (ws_size >= 130 MiB):
//   memset dp; wt_k; conv_bf16_k (enc->bf16 in ws); dec_proj_k2 (k-split, atomic);
//   gemm_scores_bf16 (m97-style global_load_lds staging, fused tanh/v-dot epilogue);
//   softmax_k; memset ctx; context_k.
// Fallback (small ws): round-2 gemm_scores (fp32 A, in-register cvt).

#define ENCD 1024
#define DECD 1024
#define BATCH 32
#define SEQ 2048
#define MTOT (BATCH * SEQ)  // 65536
#define KDIM 1024
#define NDIM 1024

typedef __attribute__((ext_vector_type(4))) float f32x4;
typedef __attribute__((ext_vector_type(8))) __bf16 bf16x8;   // mfma operand type (LLVM 'V8y')
typedef __attribute__((ext_vector_type(8))) unsigned short u16x8;

__device__ __forceinline__ unsigned short f2bf(float f) {
  unsigned int u = __builtin_bit_cast(unsigned int, f);
  u += 0x7fffu + ((u >> 16) & 1u);  // RNE
  return (unsigned short)(u >> 16);
}

// async 16B/lane global->LDS DMA. LDS dest = wave-uniform base + lane*16.
__device__ __forceinline__ void async_lds16(const unsigned short* g, unsigned short* l) {
  __builtin_amdgcn_global_load_lds(
      (const __attribute__((address_space(1))) unsigned int*)g,
      (__attribute__((address_space(3))) unsigned int*)l, 16, 0, 0);
}

// ---------------- enc fp32 -> bf16 (one pass, memory-bound) ----------------
__global__ void conv_bf16_k(const float* __restrict__ src, unsigned short* __restrict__ dst) {
  const long i = ((long)blockIdx.x * 256 + threadIdx.x) * 8;  // 64Mi elems total
  const f32x4 f0 = *(const f32x4*)(src + i);
  const f32x4 f1 = *(const f32x4*)(src + i + 4);
  u16x8 v;
  v[0] = f2bf(f0[0]); v[1] = f2bf(f0[1]); v[2] = f2bf(f0[2]); v[3] = f2bf(f0[3]);
  v[4] = f2bf(f1[0]); v[5] = f2bf(f1[1]); v[6] = f2bf(f1[2]); v[7] = f2bf(f1[3]);
  *(u16x8*)(dst + i) = v;
}

// ---------------- W_enc transpose + bf16 convert: Wt[n][k] ----------------
__global__ void wt_k(const float* __restrict__ W, unsigned short* __restrict__ Wt) {
  __shared__ unsigned short t[64][65];
  const int k0 = blockIdx.x * 64, n0 = blockIdx.y * 64;
  const int tx = threadIdx.x & 63, ty = threadIdx.x >> 6;  // 64 x 4
#pragma unroll
  for (int i = 0; i < 16; ++i) {
    const int k = ty + i * 4;
    t[k][tx] = f2bf(W[(long)(DECD + k0 + k) * NDIM + n0 + tx]);  // coalesced along n
  }
  __syncthreads();
#pragma unroll
  for (int i = 0; i < 16; ++i) {
    const int n = ty + i * 4;
    Wt[(long)(n0 + n) * KDIM + k0 + tx] = t[tx][n];  // coalesced along k
  }
}

// ---------------- dec_proj, k-split x8, atomicAdd into zeroed dp ----------------
__global__ void dec_proj_k2(const float* __restrict__ dec, const float* __restrict__ W,
                            float* __restrict__ dp) {
  const int idx = blockIdx.x * 256 + threadIdx.x;  // 32768 (b,n) pairs
  const int kc = blockIdx.y;                       // 8 k-chunks of 128
  const int b = idx >> 10;
  const int n = idx & 1023;
  const float* d = dec + b * DECD + kc * 128;
  const float* w = W + (long)(kc * 128) * NDIM + n;
  float acc = 0.f;
#pragma unroll 8
  for (int k = 0; k < 128; ++k) acc = fmaf(d[k], w[(long)k * NDIM], acc);
  atomicAdd(&dp[idx], acc);
}

// ---------------- fast GEMM: bf16 A + global_load_lds staging ----------------
// C[m][n] = sum_k Abf[m][k] * Wt[n][k]; scores[m] += sum_n tanh(C+dp+bias)*v[n]
__global__ __launch_bounds__(256, 3) void gemm_scores_bf16(
    const unsigned short* __restrict__ Abf, const unsigned short* __restrict__ Wt,
    const float* __restrict__ dp, const float* __restrict__ bias,
    const float* __restrict__ vw, float* __restrict__ scores) {
  __shared__ unsigned short sA[128 * 64];  // [row][slot*8], slot holds global chunk slot^(row&7)
  __shared__ unsigned short sB[128 * 64];

  const int tid = threadIdx.x;
  const int lane = tid & 63;
  const int wave = tid >> 6;
  const int wm = wave >> 1, wn = wave & 1;   // 2x2 waves of 64x64
  const int quad = lane >> 4;
  const int l15 = lane & 15;

  const int bn = blockIdx.x;            // 0..7  fastest: A-tile L2/L3 reuse
  const int bm = blockIdx.y;            // 0..511
  const int n0 = bn * 128;
  const int row0 = bm * 128;
  const int bidx = bm >> 4;             // batch index (BM=128 divides S=2048)

  // DMA source coords: lane covers (row-in-8-group, slot); source chunk is XOR-swizzled
  const int srow = lane >> 3;                       // 0..7
  const int schunk = (lane & 7) ^ srow;             // global chunk fetched by this lane

  const f32x4 zz = {0.f, 0.f, 0.f, 0.f};
  f32x4 acc[4][4];
#pragma unroll
  for (int i = 0; i < 4; ++i)
#pragma unroll
    for (int j = 0; j < 4; ++j) acc[i][j] = zz;

  for (int kt = 0; kt < 16; ++kt) {
    const int k0 = kt * 64;
    __syncthreads();  // all waves' ds_reads of previous tile done
#pragma unroll
    for (int i = 0; i < 4; ++i) {
      const int r = wave * 32 + i * 8 + srow;  // LDS-local row this lane sources
      async_lds16(Abf + (size_t)(row0 + r) * KDIM + k0 + schunk * 8,
                  &sA[(wave * 32 + i * 8) * 64]);
      async_lds16(Wt + (size_t)(n0 + r) * KDIM + k0 + schunk * 8,
                  &sB[(wave * 32 + i * 8) * 64]);
    }
    __syncthreads();  // compiler drains vmcnt(0) before barrier -> LDS ready
#pragma unroll
    for (int h = 0; h < 2; ++h) {
      bf16x8 af[4], bf[4];
      const int slot = ((h * 4 + quad) ^ (l15 & 7)) * 8;  // un-swizzle on read
#pragma unroll
      for (int t = 0; t < 4; ++t) {
        af[t] = __builtin_bit_cast(bf16x8, *(const u16x8*)&sA[(wm * 64 + t * 16 + l15) * 64 + slot]);
        bf[t] = __builtin_bit_cast(bf16x8, *(const u16x8*)&sB[(wn * 64 + t * 16 + l15) * 64 + slot]);
      }
#pragma unroll
      for (int mt = 0; mt < 4; ++mt)
#pragma unroll
        for (int nt = 0; nt < 4; ++nt)
          acc[mt][nt] = __builtin_amdgcn_mfma_f32_16x16x32_bf16(
              af[mt], bf[nt], acc[mt][nt], 0, 0, 0);
    }
  }

  // Epilogue: s[m] += sum_n tanh(C + dp + bias) * v[n]
  float vv[4], dv[4];
#pragma unroll
  for (int nt = 0; nt < 4; ++nt) {
    const int n = n0 + wn * 64 + nt * 16 + l15;
    vv[nt] = vw[n];
    dv[nt] = dp[bidx * NDIM + n] + bias[n];
  }
#pragma unroll
  for (int mt = 0; mt < 4; ++mt) {
#pragma unroll
    for (int r = 0; r < 4; ++r) {
      float s = 0.f;
#pragma unroll
      for (int nt = 0; nt < 4; ++nt) {
        float x = acc[mt][nt][r] + dv[nt];
        x = fminf(fmaxf(x, -10.f), 10.f);
        const float e = __expf(2.f * x);
        s += (e - 1.f) * __builtin_amdgcn_rcpf(e + 1.f) * vv[nt];  // tanh
      }
      s += __shfl_xor(s, 1);
      s += __shfl_xor(s, 2);
      s += __shfl_xor(s, 4);
      s += __shfl_xor(s, 8);
      if (l15 == 0) {
        const int m = row0 + wm * 64 + mt * 16 + quad * 4 + r;  // C row = quad*4+reg
        atomicAdd(&scores[m], s);
      }
    }
  }
}

// ---------------- fallback GEMM (round-2, fp32 A, in-register cvt) ----------------
__global__ __launch_bounds__(256, 2) void gemm_scores(
    const float* __restrict__ Ag, const unsigned short* __restrict__ Wt,
    const float* __restrict__ dp, const float* __restrict__ bias,
    const float* __restrict__ vw, float* __restrict__ scores) {
  __shared__ unsigned short sA[128 * 64];
  __shared__ unsigned short sB[128 * 64];
  const int tid = threadIdx.x;
  const int lane = tid & 63;
  const int wave = tid >> 6;
  const int wm = wave >> 1, wn = wave & 1;
  const int quad = lane >> 4;
  const int l15 = lane & 15;
  const int bn = blockIdx.x, bm = blockIdx.y;
  const int n0 = bn * 128, row0 = bm * 128, bidx = bm >> 4;
  const int sr = tid >> 3, sc = tid & 7;

  const f32x4 zz = {0.f, 0.f, 0.f, 0.f};
  f32x4 acc[4][4];
#pragma unroll
  for (int i = 0; i < 4; ++i)
#pragma unroll
    for (int j = 0; j < 4; ++j) acc[i][j] = zz;

  for (int kt = 0; kt < 16; ++kt) {
    const int k0 = kt * 64;
    __syncthreads();
#pragma unroll
    for (int j = 0; j < 4; ++j) {
      const int r = sr + 32 * j;
      const int c = sc ^ (r & 7);
      const float* src = Ag + (long)(row0 + r) * KDIM + (k0 + c * 8);
      f32x4 f0 = *(const f32x4*)src;
      f32x4 f1 = *(const f32x4*)(src + 4);
      u16x8 v;
      v[0] = f2bf(f0[0]); v[1] = f2bf(f0[1]); v[2] = f2bf(f0[2]); v[3] = f2bf(f0[3]);
      v[4] = f2bf(f1[0]); v[5] = f2bf(f1[1]); v[6] = f2bf(f1[2]); v[7] = f2bf(f1[3]);
      *(u16x8*)&sA[r * 64 + sc * 8] = v;
      const unsigned short* srcB = Wt + (long)(n0 + r) * KDIM + (k0 + c * 8);
      *(u16x8*)&sB[r * 64 + sc * 8] = *(const u16x8*)srcB;
    }
    __syncthreads();
#pragma unroll
    for (int h = 0; h < 2; ++h) {
      const int cs = ((h * 4 + quad) ^ (lane & 7)) * 8;
      bf16x8 af[4], bf[4];
#pragma unroll
      for (int t = 0; t < 4; ++t) {
        af[t] = __builtin_bit_cast(bf16x8, *(const u16x8*)&sA[(wm * 64 + t * 16 + l15) * 64 + cs]);
        bf[t] = __builtin_bit_cast(bf16x8, *(const u16x8*)&sB[(wn * 64 + t * 16 + l15) * 64 + cs]);
      }
#pragma unroll
      for (int mt = 0; mt < 4; ++mt)
#pragma unroll
        for (int nt = 0; nt < 4; ++nt)
          acc[mt][nt] = __builtin_amdgcn_mfma_f32_16x16x32_bf16(
              af[mt], bf[nt], acc[mt][nt], 0, 0, 0);
    }
  }

  float vv[4], dv[4];
#pragma unroll
  for (int nt = 0; nt < 4; ++nt) {
    const int n = n0 + wn * 64 + nt * 16 + l15;
    vv[nt] = vw[n];
    dv[nt] = dp[bidx * NDIM + n] + bias[n];
  }
#pragma unroll
  for (int mt = 0; mt < 4; ++mt) {
#pragma unroll
    for (int r = 0; r < 4; ++r) {
      float s = 0.f;
#pragma unroll
      for (int nt = 0; nt < 4; ++nt) {
        float x = acc[mt][nt][r] + dv[nt];
        x = fminf(fmaxf(x, -10.f), 10.f);
        const float e = __expf(2.f * x);
        s += (e - 1.f) * __builtin_amdgcn_rcpf(e + 1.f) * vv[nt];
      }
      s += __shfl_xor(s, 1);
      s += __shfl_xor(s, 2);
      s += __shfl_xor(s, 4);
      s += __shfl_xor(s, 8);
      if (l15 == 0) {
        const int m = row0 + wm * 64 + mt * 16 + quad * 4 + r;
        atomicAdd(&scores[m], s);
      }
    }
  }
}

// ---------------- masked softmax, in-place on scores ----------------
__global__ void softmax_k(float* __restrict__ sc, const int* __restrict__ mask) {
  const int b = blockIdx.x;
  const int tid = threadIdx.x;
  const int w = tid >> 6;
  __shared__ float redm[4], reds[4];
  float* row = sc + b * SEQ;
  const int* mrow = mask + b * SEQ;
  float vals[8];
  float mx = -3.0e38f;
#pragma unroll
  for (int i = 0; i < 8; ++i) {
    const int s = tid + i * 256;
    float v = row[s];
    if (mrow[s] == 0) v = -1.0e9f;
    vals[i] = v;
    mx = fmaxf(mx, v);
  }
#pragma unroll
  for (int off = 1; off < 64; off <<= 1) mx = fmaxf(mx, __shfl_xor(mx, off));
  if ((tid & 63) == 0) redm[w] = mx;
  __syncthreads();
  mx = fmaxf(fmaxf(redm[0], redm[1]), fmaxf(redm[2], redm[3]));
  float sum = 0.f;
#pragma unroll
  for (int i = 0; i < 8; ++i) {
    vals[i] = __expf(vals[i] - mx);
    sum += vals[i];
  }
#pragma unroll
  for (int off = 1; off < 64; off <<= 1) sum += __shfl_xor(sum, off);
  if ((tid & 63) == 0) reds[w] = sum;
  __syncthreads();
  sum = reds[0] + reds[1] + reds[2] + reds[3];
  const float inv = 1.0f / sum;
#pragma unroll
  for (int i = 0; i < 8; ++i) row[tid + i * 256] = vals[i] * inv;
}

// ---------------- context = attn @ enc (fp32, memory-bound) ----------------
__global__ void context_k(const float* __restrict__ attn, const float* __restrict__ enc,
                          float* __restrict__ ctx) {
  const int b = blockIdx.y;          // 32
  const int s0 = blockIdx.x * 32;    // 64 s-chunks -> 2048 blocks (8/CU)
  const int e = threadIdx.x * 4;
  const float* arow = attn + b * SEQ + s0;
  const float* ebase = enc + (long)(b * SEQ + s0) * ENCD + e;
  f32x4 acc = {0.f, 0.f, 0.f, 0.f};
#pragma unroll 8
  for (int s = 0; s < 32; ++s) {
    const float w = arow[s];
    const f32x4 v = *(const f32x4*)(ebase + (long)s * ENCD);
    acc += w * v;
  }
  float* dst = ctx + b * ENCD + e;
  atomicAdd(dst + 0, acc[0]);
  atomicAdd(dst + 1, acc[1]);
  atomicAdd(dst + 2, acc[2]);
  atomicAdd(dst + 3, acc[3]);
}

extern "C" void kernel_launch(void* const* d_in, const int* in_sizes, int n_in,
                              void* d_out, int out_size, void* d_ws, size_t ws_size,
                              hipStream_t stream) {
  (void)in_sizes; (void)n_in; (void)out_size;
  const float* dec  = (const float*)d_in[0];
  const float* enc  = (const float*)d_in[1];
  const int*   mask = (const int*)d_in[2];
  const float* W    = (const float*)d_in[3];
  const float* bias = (const float*)d_in[4];
  const float* vw   = (const float*)d_in[5];

  float* ctx    = (float*)d_out;                   // context region: 32*1024 (dp parked here first)
  float* scores = (float*)d_out + BATCH * ENCD;    // attn region: 32*2048 (scores in-place)
  unsigned short* Wt  = (unsigned short*)d_ws;                       // 2 MiB
  unsigned short* Abf = (unsigned short*)((char*)d_ws + (2u << 20)); // 128 MiB

  const bool fast = ws_size >= ((2ull << 20) + ((size_t)MTOT * KDIM * 2));

  hipMemsetAsync(scores, 0, (size_t)MTOT * sizeof(float), stream);
  hipMemsetAsync(ctx, 0, (size_t)(BATCH * NDIM) * sizeof(float), stream);  // dp = 0
  wt_k<<<dim3(16, 16), 256, 0, stream>>>(W, Wt);
  dec_proj_k2<<<dim3(128, 8), 256, 0, stream>>>(dec, W, ctx);
  if (fast) {
    conv_bf16_k<<<32768, 256, 0, stream>>>(enc, Abf);
    gemm_scores_bf16<<<dim3(8, 512), 256, 0, stream>>>(Abf, Wt, ctx, bias, vw, scores);
  } else {
    gemm_scores<<<dim3(8, 512), 256, 0, stream>>>(enc, Wt, ctx, bias, vw, scores);
  }
  softmax_k<<<32, 256, 0, stream>>>(scores, mask);
  hipMemsetAsync(ctx, 0, (size_t)(BATCH * ENCD) * sizeof(float), stream);
  context_k<<<dim3(64, 32), 256, 0, stream>>>(scores, enc, ctx);
}

// Round 4
// 569.169 us; speedup vs baseline: 1.4455x; 1.0712x over previous
//
#include <hip/hip_runtime.h>
#include <hip/hip_bf16.h>
#include <cstdint>

// BahdanauAttention on MI355X — round 4: atomic-free, memset-free fast path.
// Fast path A (ws >= 132 MiB):
//   wt_k; conv_bf16_k; dec1_k (k-split partials); dec2_k (reduce + bias -> dp in d_out ctx region);
//   gemm_fast (bf16 A via global_load_lds, plain-store score partials sp[bn][m]);
//   softmax_part_k (sum 8 partials + mask + softmax -> attn region);
//   ctx1_k (attn @ bf16 Abf -> 16 s-chunk partials); ctx2_k (reduce -> ctx).
// Path B (ws >= 130 MiB): proven round-3 pipeline (atomics + memsets).
// Path C: round-2 pipeline (fp32 A in-register cvt).

#define ENCD 1024
#define DECD 1024
#define BATCH 32
#define SEQ 2048
#define MTOT (BATCH * SEQ)  // 65536
#define KDIM 1024
#define NDIM 1024

typedef __attribute__((ext_vector_type(4))) float f32x4;
typedef __attribute__((ext_vector_type(8))) __bf16 bf16x8;
typedef __attribute__((ext_vector_type(8))) unsigned short u16x8;

__device__ __forceinline__ unsigned short f2bf(float f) {
  unsigned int u = __builtin_bit_cast(unsigned int, f);
  u += 0x7fffu + ((u >> 16) & 1u);  // RNE
  return (unsigned short)(u >> 16);
}

__device__ __forceinline__ float bf2f(unsigned short h) {
  return __builtin_bit_cast(float, (unsigned int)h << 16);
}

// async 16B/lane global->LDS DMA. LDS dest = wave-uniform base + lane*16.
__device__ __forceinline__ void async_lds16(const unsigned short* g, unsigned short* l) {
  __builtin_amdgcn_global_load_lds(
      (const __attribute__((address_space(1))) unsigned int*)g,
      (__attribute__((address_space(3))) unsigned int*)l, 16, 0, 0);
}

// ---------------- enc fp32 -> bf16 (one pass, memory-bound) ----------------
__global__ void conv_bf16_k(const float* __restrict__ src, unsigned short* __restrict__ dst) {
  const long i = ((long)blockIdx.x * 256 + threadIdx.x) * 8;
  const f32x4 f0 = *(const f32x4*)(src + i);
  const f32x4 f1 = *(const f32x4*)(src + i + 4);
  u16x8 v;
  v[0] = f2bf(f0[0]); v[1] = f2bf(f0[1]); v[2] = f2bf(f0[2]); v[3] = f2bf(f0[3]);
  v[4] = f2bf(f1[0]); v[5] = f2bf(f1[1]); v[6] = f2bf(f1[2]); v[7] = f2bf(f1[3]);
  *(u16x8*)(dst + i) = v;
}

// ---------------- W_enc transpose + bf16 convert: Wt[n][k] ----------------
__global__ void wt_k(const float* __restrict__ W, unsigned short* __restrict__ Wt) {
  __shared__ unsigned short t[64][65];
  const int k0 = blockIdx.x * 64, n0 = blockIdx.y * 64;
  const int tx = threadIdx.x & 63, ty = threadIdx.x >> 6;
#pragma unroll
  for (int i = 0; i < 16; ++i) {
    const int k = ty + i * 4;
    t[k][tx] = f2bf(W[(long)(DECD + k0 + k) * NDIM + n0 + tx]);
  }
  __syncthreads();
#pragma unroll
  for (int i = 0; i < 16; ++i) {
    const int n = ty + i * 4;
    Wt[(long)(n0 + n) * KDIM + k0 + tx] = t[tx][n];
  }
}

// ---------------- dec_proj fast: k-split partials, no atomics ----------------
__global__ void dec1_k(const float* __restrict__ dec, const float* __restrict__ W,
                       float* __restrict__ part) {
  const int idx = blockIdx.x * 256 + threadIdx.x;  // 32768 (b,n)
  const int kc = blockIdx.y;                       // 8 chunks of 128
  const int b = idx >> 10;
  const int n = idx & 1023;
  const float* d = dec + b * DECD + kc * 128;
  const float* w = W + (long)(kc * 128) * NDIM + n;
  float acc = 0.f;
#pragma unroll 8
  for (int k = 0; k < 128; ++k) acc = fmaf(d[k], w[(long)k * NDIM], acc);
  part[kc * 32768 + idx] = acc;
}

__global__ void dec2_k(const float* __restrict__ part, const float* __restrict__ bias,
                       float* __restrict__ dp) {
  const int idx = blockIdx.x * 256 + threadIdx.x;  // 32768
  float s = bias[idx & 1023];
#pragma unroll
  for (int kc = 0; kc < 8; ++kc) s += part[kc * 32768 + idx];
  dp[idx] = s;
}

// ---------------- fast GEMM: bf16 A, global_load_lds, plain-store partials ----------------
// sp[bn][m] = sum over this block's n-half-pair of tanh(C+dp)*v  (dp includes bias)
__global__ __launch_bounds__(256, 4) void gemm_fast(
    const unsigned short* __restrict__ Abf, const unsigned short* __restrict__ Wt,
    const float* __restrict__ dp, const float* __restrict__ vw,
    float* __restrict__ sp) {
  __shared__ unsigned short sA[128 * 64];
  __shared__ unsigned short sB[128 * 64];

  const int tid = threadIdx.x;
  const int lane = tid & 63;
  const int wave = tid >> 6;
  const int wm = wave >> 1, wn = wave & 1;
  const int quad = lane >> 4;
  const int l15 = lane & 15;

  const int bn = blockIdx.x;   // 0..7
  const int bm = blockIdx.y;   // 0..511
  const int n0 = bn * 128;
  const int row0 = bm * 128;
  const int bidx = bm >> 4;

  const int srow = lane >> 3;
  const int schunk = (lane & 7) ^ srow;

  const f32x4 zz = {0.f, 0.f, 0.f, 0.f};
  f32x4 acc[4][4];
#pragma unroll
  for (int i = 0; i < 4; ++i)
#pragma unroll
    for (int j = 0; j < 4; ++j) acc[i][j] = zz;

  for (int kt = 0; kt < 16; ++kt) {
    const int k0 = kt * 64;
    __syncthreads();
#pragma unroll
    for (int i = 0; i < 4; ++i) {
      const int r = wave * 32 + i * 8 + srow;
      async_lds16(Abf + (size_t)(row0 + r) * KDIM + k0 + schunk * 8,
                  &sA[(wave * 32 + i * 8) * 64]);
      async_lds16(Wt + (size_t)(n0 + r) * KDIM + k0 + schunk * 8,
                  &sB[(wave * 32 + i * 8) * 64]);
    }
    __syncthreads();
#pragma unroll
    for (int h = 0; h < 2; ++h) {
      bf16x8 af[4], bf[4];
      const int slot = ((h * 4 + quad) ^ (l15 & 7)) * 8;
#pragma unroll
      for (int t = 0; t < 4; ++t) {
        af[t] = __builtin_bit_cast(bf16x8, *(const u16x8*)&sA[(wm * 64 + t * 16 + l15) * 64 + slot]);
        bf[t] = __builtin_bit_cast(bf16x8, *(const u16x8*)&sB[(wn * 64 + t * 16 + l15) * 64 + slot]);
      }
#pragma unroll
      for (int mt = 0; mt < 4; ++mt)
#pragma unroll
        for (int nt = 0; nt < 4; ++nt)
          acc[mt][nt] = __builtin_amdgcn_mfma_f32_16x16x32_bf16(
              af[mt], bf[nt], acc[mt][nt], 0, 0, 0);
    }
  }

  // Epilogue: per-row tanh/v-dot partial; reduce wn=1 into wn=0 via LDS; plain store.
  float vv[4], dv[4];
#pragma unroll
  for (int nt = 0; nt < 4; ++nt) {
    const int n = n0 + wn * 64 + nt * 16 + l15;
    vv[nt] = vw[n];
    dv[nt] = dp[bidx * NDIM + n];  // bias already folded in
  }
  float s_arr[4][4];
#pragma unroll
  for (int mt = 0; mt < 4; ++mt) {
#pragma unroll
    for (int r = 0; r < 4; ++r) {
      float s = 0.f;
#pragma unroll
      for (int nt = 0; nt < 4; ++nt) {
        float x = acc[mt][nt][r] + dv[nt];
        x = fminf(fmaxf(x, -10.f), 10.f);
        const float e = __expf(2.f * x);
        s += (e - 1.f) * __builtin_amdgcn_rcpf(e + 1.f) * vv[nt];  // tanh
      }
      s += __shfl_xor(s, 1);
      s += __shfl_xor(s, 2);
      s += __shfl_xor(s, 4);
      s += __shfl_xor(s, 8);
      s_arr[mt][r] = s;
    }
  }
  __syncthreads();  // k-loop LDS reads done everywhere; sA reusable
  float* sRed = (float*)sA;
  if (wn == 1 && l15 == 0) {
#pragma unroll
    for (int mt = 0; mt < 4; ++mt)
#pragma unroll
      for (int r = 0; r < 4; ++r)
        sRed[wm * 64 + mt * 16 + quad * 4 + r] = s_arr[mt][r];
  }
  __syncthreads();
  if (wn == 0 && l15 == 0) {
#pragma unroll
    for (int mt = 0; mt < 4; ++mt)
#pragma unroll
      for (int r = 0; r < 4; ++r) {
        const int ml = wm * 64 + mt * 16 + quad * 4 + r;
        sp[(size_t)bn * MTOT + row0 + ml] = s_arr[mt][r] + sRed[ml];
      }
  }
}

// ---------------- softmax over summed partials -> attn ----------------
__global__ void softmax_part_k(const float* __restrict__ sp, const int* __restrict__ mask,
                               float* __restrict__ attn) {
  const int b = blockIdx.x;
  const int tid = threadIdx.x;
  const int w = tid >> 6;
  __shared__ float redm[4], reds[4];
  const int* mrow = mask + b * SEQ;
  float vals[8];
  float mx = -3.0e38f;
#pragma unroll
  for (int i = 0; i < 8; ++i) {
    const int s = tid + i * 256;
    float v = 0.f;
#pragma unroll
    for (int bn = 0; bn < 8; ++bn) v += sp[(size_t)bn * MTOT + b * SEQ + s];
    if (mrow[s] == 0) v = -1.0e9f;
    vals[i] = v;
    mx = fmaxf(mx, v);
  }
#pragma unroll
  for (int off = 1; off < 64; off <<= 1) mx = fmaxf(mx, __shfl_xor(mx, off));
  if ((tid & 63) == 0) redm[w] = mx;
  __syncthreads();
  mx = fmaxf(fmaxf(redm[0], redm[1]), fmaxf(redm[2], redm[3]));
  float sum = 0.f;
#pragma unroll
  for (int i = 0; i < 8; ++i) {
    vals[i] = __expf(vals[i] - mx);
    sum += vals[i];
  }
#pragma unroll
  for (int off = 1; off < 64; off <<= 1) sum += __shfl_xor(sum, off);
  if ((tid & 63) == 0) reds[w] = sum;
  __syncthreads();
  sum = reds[0] + reds[1] + reds[2] + reds[3];
  const float inv = 1.0f / sum;
#pragma unroll
  for (int i = 0; i < 8; ++i) attn[b * SEQ + tid + i * 256] = vals[i] * inv;
}

// ---------------- context stage 1: bf16 enc, s-chunk partials ----------------
__global__ void ctx1_k(const float* __restrict__ attn, const unsigned short* __restrict__ Abf,
                       float* __restrict__ part) {
  const int sc = blockIdx.x;  // 16 chunks of 128 s
  const int b = blockIdx.y;   // 32
  const int e0 = threadIdx.x * 8;  // 128 threads * 8 = 1024
  const float* arow = attn + b * SEQ + sc * 128;
  const unsigned short* base = Abf + (size_t)(b * SEQ + sc * 128) * ENCD + e0;
  float acc[8] = {0.f, 0.f, 0.f, 0.f, 0.f, 0.f, 0.f, 0.f};
#pragma unroll 8
  for (int s = 0; s < 128; ++s) {
    const float w = arow[s];
    const u16x8 v = *(const u16x8*)(base + (size_t)s * ENCD);
#pragma unroll
    for (int j = 0; j < 8; ++j) acc[j] = fmaf(w, bf2f(v[j]), acc[j]);
  }
  float* dst = part + (size_t)sc * (BATCH * ENCD) + b * ENCD + e0;
  *(f32x4*)dst = *(f32x4*)&acc[0];
  *(f32x4*)(dst + 4) = *(f32x4*)&acc[4];
}

__global__ void ctx2_k(const float* __restrict__ part, float* __restrict__ ctx) {
  const int i = blockIdx.x * 256 + threadIdx.x;  // 32768
  float s = 0.f;
#pragma unroll
  for (int c = 0; c < 16; ++c) s += part[(size_t)c * (BATCH * ENCD) + i];
  ctx[i] = s;
}

// ================= Path B/C fallback kernels (round-3 proven) =================
__global__ void dec_proj_k2(const float* __restrict__ dec, const float* __restrict__ W,
                            float* __restrict__ dp) {
  const int idx = blockIdx.x * 256 + threadIdx.x;
  const int kc = blockIdx.y;
  const int b = idx >> 10;
  const int n = idx & 1023;
  const float* d = dec + b * DECD + kc * 128;
  const float* w = W + (long)(kc * 128) * NDIM + n;
  float acc = 0.f;
#pragma unroll 8
  for (int k = 0; k < 128; ++k) acc = fmaf(d[k], w[(long)k * NDIM], acc);
  atomicAdd(&dp[idx], acc);
}

__global__ __launch_bounds__(256, 3) void gemm_scores_bf16(
    const unsigned short* __restrict__ Abf, const unsigned short* __restrict__ Wt,
    const float* __restrict__ dp, const float* __restrict__ bias,
    const float* __restrict__ vw, float* __restrict__ scores) {
  __shared__ unsigned short sA[128 * 64];
  __shared__ unsigned short sB[128 * 64];
  const int tid = threadIdx.x;
  const int lane = tid & 63;
  const int wave = tid >> 6;
  const int wm = wave >> 1, wn = wave & 1;
  const int quad = lane >> 4;
  const int l15 = lane & 15;
  const int bn = blockIdx.x, bm = blockIdx.y;
  const int n0 = bn * 128, row0 = bm * 128, bidx = bm >> 4;
  const int srow = lane >> 3;
  const int schunk = (lane & 7) ^ srow;
  const f32x4 zz = {0.f, 0.f, 0.f, 0.f};
  f32x4 acc[4][4];
#pragma unroll
  for (int i = 0; i < 4; ++i)
#pragma unroll
    for (int j = 0; j < 4; ++j) acc[i][j] = zz;
  for (int kt = 0; kt < 16; ++kt) {
    const int k0 = kt * 64;
    __syncthreads();
#pragma unroll
    for (int i = 0; i < 4; ++i) {
      const int r = wave * 32 + i * 8 + srow;
      async_lds16(Abf + (size_t)(row0 + r) * KDIM + k0 + schunk * 8,
                  &sA[(wave * 32 + i * 8) * 64]);
      async_lds16(Wt + (size_t)(n0 + r) * KDIM + k0 + schunk * 8,
                  &sB[(wave * 32 + i * 8) * 64]);
    }
    __syncthreads();
#pragma unroll
    for (int h = 0; h < 2; ++h) {
      bf16x8 af[4], bf[4];
      const int slot = ((h * 4 + quad) ^ (l15 & 7)) * 8;
#pragma unroll
      for (int t = 0; t < 4; ++t) {
        af[t] = __builtin_bit_cast(bf16x8, *(const u16x8*)&sA[(wm * 64 + t * 16 + l15) * 64 + slot]);
        bf[t] = __builtin_bit_cast(bf16x8, *(const u16x8*)&sB[(wn * 64 + t * 16 + l15) * 64 + slot]);
      }
#pragma unroll
      for (int mt = 0; mt < 4; ++mt)
#pragma unroll
        for (int nt = 0; nt < 4; ++nt)
          acc[mt][nt] = __builtin_amdgcn_mfma_f32_16x16x32_bf16(
              af[mt], bf[nt], acc[mt][nt], 0, 0, 0);
    }
  }
  float vv[4], dv[4];
#pragma unroll
  for (int nt = 0; nt < 4; ++nt) {
    const int n = n0 + wn * 64 + nt * 16 + l15;
    vv[nt] = vw[n];
    dv[nt] = dp[bidx * NDIM + n] + bias[n];
  }
#pragma unroll
  for (int mt = 0; mt < 4; ++mt) {
#pragma unroll
    for (int r = 0; r < 4; ++r) {
      float s = 0.f;
#pragma unroll
      for (int nt = 0; nt < 4; ++nt) {
        float x = acc[mt][nt][r] + dv[nt];
        x = fminf(fmaxf(x, -10.f), 10.f);
        const float e = __expf(2.f * x);
        s += (e - 1.f) * __builtin_amdgcn_rcpf(e + 1.f) * vv[nt];
      }
      s += __shfl_xor(s, 1);
      s += __shfl_xor(s, 2);
      s += __shfl_xor(s, 4);
      s += __shfl_xor(s, 8);
      if (l15 == 0) atomicAdd(&scores[row0 + wm * 64 + mt * 16 + quad * 4 + r], s);
    }
  }
}

__global__ __launch_bounds__(256, 2) void gemm_scores_f32(
    const float* __restrict__ Ag, const unsigned short* __restrict__ Wt,
    const float* __restrict__ dp, const float* __restrict__ bias,
    const float* __restrict__ vw, float* __restrict__ scores) {
  __shared__ unsigned short sA[128 * 64];
  __shared__ unsigned short sB[128 * 64];
  const int tid = threadIdx.x;
  const int lane = tid & 63;
  const int wave = tid >> 6;
  const int wm = wave >> 1, wn = wave & 1;
  const int quad = lane >> 4;
  const int l15 = lane & 15;
  const int bn = blockIdx.x, bm = blockIdx.y;
  const int n0 = bn * 128, row0 = bm * 128, bidx = bm >> 4;
  const int sr = tid >> 3, sc = tid & 7;
  const f32x4 zz = {0.f, 0.f, 0.f, 0.f};
  f32x4 acc[4][4];
#pragma unroll
  for (int i = 0; i < 4; ++i)
#pragma unroll
    for (int j = 0; j < 4; ++j) acc[i][j] = zz;
  for (int kt = 0; kt < 16; ++kt) {
    const int k0 = kt * 64;
    __syncthreads();
#pragma unroll
    for (int j = 0; j < 4; ++j) {
      const int r = sr + 32 * j;
      const int c = sc ^ (r & 7);
      const float* src = Ag + (long)(row0 + r) * KDIM + (k0 + c * 8);
      f32x4 f0 = *(const f32x4*)src;
      f32x4 f1 = *(const f32x4*)(src + 4);
      u16x8 v;
      v[0] = f2bf(f0[0]); v[1] = f2bf(f0[1]); v[2] = f2bf(f0[2]); v[3] = f2bf(f0[3]);
      v[4] = f2bf(f1[0]); v[5] = f2bf(f1[1]); v[6] = f2bf(f1[2]); v[7] = f2bf(f1[3]);
      *(u16x8*)&sA[r * 64 + sc * 8] = v;
      *(u16x8*)&sB[r * 64 + sc * 8] = *(const u16x8*)(Wt + (long)(n0 + r) * KDIM + (k0 + c * 8));
    }
    __syncthreads();
#pragma unroll
    for (int h = 0; h < 2; ++h) {
      const int cs = ((h * 4 + quad) ^ (lane & 7)) * 8;
      bf16x8 af[4], bf[4];
#pragma unroll
      for (int t = 0; t < 4; ++t) {
        af[t] = __builtin_bit_cast(bf16x8, *(const u16x8*)&sA[(wm * 64 + t * 16 + l15) * 64 + cs]);
        bf[t] = __builtin_bit_cast(bf16x8, *(const u16x8*)&sB[(wn * 64 + t * 16 + l15) * 64 + cs]);
      }
#pragma unroll
      for (int mt = 0; mt < 4; ++mt)
#pragma unroll
        for (int nt = 0; nt < 4; ++nt)
          acc[mt][nt] = __builtin_amdgcn_mfma_f32_16x16x32_bf16(
              af[mt], bf[nt], acc[mt][nt], 0, 0, 0);
    }
  }
  float vv[4], dv[4];
#pragma unroll
  for (int nt = 0; nt < 4; ++nt) {
    const int n = n0 + wn * 64 + nt * 16 + l15;
    vv[nt] = vw[n];
    dv[nt] = dp[bidx * NDIM + n] + bias[n];
  }
#pragma unroll
  for (int mt = 0; mt < 4; ++mt) {
#pragma unroll
    for (int r = 0; r < 4; ++r) {
      float s = 0.f;
#pragma unroll
      for (int nt = 0; nt < 4; ++nt) {
        float x = acc[mt][nt][r] + dv[nt];
        x = fminf(fmaxf(x, -10.f), 10.f);
        const float e = __expf(2.f * x);
        s += (e - 1.f) * __builtin_amdgcn_rcpf(e + 1.f) * vv[nt];
      }
      s += __shfl_xor(s, 1);
      s += __shfl_xor(s, 2);
      s += __shfl_xor(s, 4);
      s += __shfl_xor(s, 8);
      if (l15 == 0) atomicAdd(&scores[row0 + wm * 64 + mt * 16 + quad * 4 + r], s);
    }
  }
}

__global__ void softmax_k(float* __restrict__ sc, const int* __restrict__ mask) {
  const int b = blockIdx.x;
  const int tid = threadIdx.x;
  const int w = tid >> 6;
  __shared__ float redm[4], reds[4];
  float* row = sc + b * SEQ;
  const int* mrow = mask + b * SEQ;
  float vals[8];
  float mx = -3.0e38f;
#pragma unroll
  for (int i = 0; i < 8; ++i) {
    const int s = tid + i * 256;
    float v = row[s];
    if (mrow[s] == 0) v = -1.0e9f;
    vals[i] = v;
    mx = fmaxf(mx, v);
  }
#pragma unroll
  for (int off = 1; off < 64; off <<= 1) mx = fmaxf(mx, __shfl_xor(mx, off));
  if ((tid & 63) == 0) redm[w] = mx;
  __syncthreads();
  mx = fmaxf(fmaxf(redm[0], redm[1]), fmaxf(redm[2], redm[3]));
  float sum = 0.f;
#pragma unroll
  for (int i = 0; i < 8; ++i) {
    vals[i] = __expf(vals[i] - mx);
    sum += vals[i];
  }
#pragma unroll
  for (int off = 1; off < 64; off <<= 1) sum += __shfl_xor(sum, off);
  if ((tid & 63) == 0) reds[w] = sum;
  __syncthreads();
  sum = reds[0] + reds[1] + reds[2] + reds[3];
  const float inv = 1.0f / sum;
#pragma unroll
  for (int i = 0; i < 8; ++i) row[tid + i * 256] = vals[i] * inv;
}

__global__ void context_k(const float* __restrict__ attn, const float* __restrict__ enc,
                          float* __restrict__ ctx) {
  const int b = blockIdx.y;
  const int s0 = blockIdx.x * 32;
  const int e = threadIdx.x * 4;
  const float* arow = attn + b * SEQ + s0;
  const float* ebase = enc + (long)(b * SEQ + s0) * ENCD + e;
  f32x4 acc = {0.f, 0.f, 0.f, 0.f};
#pragma unroll 8
  for (int s = 0; s < 32; ++s) {
    const float w = arow[s];
    const f32x4 v = *(const f32x4*)(ebase + (long)s * ENCD);
    acc += w * v;
  }
  float* dst = ctx + b * ENCD + e;
  atomicAdd(dst + 0, acc[0]);
  atomicAdd(dst + 1, acc[1]);
  atomicAdd(dst + 2, acc[2]);
  atomicAdd(dst + 3, acc[3]);
}

extern "C" void kernel_launch(void* const* d_in, const int* in_sizes, int n_in,
                              void* d_out, int out_size, void* d_ws, size_t ws_size,
                              hipStream_t stream) {
  (void)in_sizes; (void)n_in; (void)out_size;
  const float* dec  = (const float*)d_in[0];
  const float* enc  = (const float*)d_in[1];
  const int*   mask = (const int*)d_in[2];
  const float* W    = (const float*)d_in[3];
  const float* bias = (const float*)d_in[4];
  const float* vw   = (const float*)d_in[5];

  float* ctx  = (float*)d_out;                 // context region (also dp parking)
  float* attn = (float*)d_out + BATCH * ENCD;  // attn region (scores in-place for B/C)
  unsigned short* Wt  = (unsigned short*)d_ws;                         // 2 MiB
  unsigned short* Abf = (unsigned short*)((char*)d_ws + (2ull << 20)); // 128 MiB
  float* shared = (float*)((char*)d_ws + (130ull << 20));              // 2 MiB multi-use

  const size_t needA = (132ull << 20);
  const size_t needB = (2ull << 20) + ((size_t)MTOT * KDIM * 2);

  wt_k<<<dim3(16, 16), 256, 0, stream>>>(W, Wt);
  if (ws_size >= needA) {
    // dp_part -> shared (1 MiB), then dp -> ctx region
    dec1_k<<<dim3(128, 8), 256, 0, stream>>>(dec, W, shared);
    dec2_k<<<128, 256, 0, stream>>>(shared, bias, ctx);
    conv_bf16_k<<<32768, 256, 0, stream>>>(enc, Abf);
    // score partials sp[8][65536] -> shared (2 MiB)
    gemm_fast<<<dim3(8, 512), 256, 0, stream>>>(Abf, Wt, ctx, vw, shared);
    softmax_part_k<<<32, 256, 0, stream>>>(shared, mask, attn);
    // ctx partials [16][32768] -> shared (2 MiB)
    ctx1_k<<<dim3(16, 32), 128, 0, stream>>>(attn, Abf, shared);
    ctx2_k<<<128, 256, 0, stream>>>(shared, ctx);
  } else if (ws_size >= needB) {
    hipMemsetAsync(attn, 0, (size_t)MTOT * sizeof(float), stream);
    hipMemsetAsync(ctx, 0, (size_t)(BATCH * NDIM) * sizeof(float), stream);
    dec_proj_k2<<<dim3(128, 8), 256, 0, stream>>>(dec, W, ctx);
    conv_bf16_k<<<32768, 256, 0, stream>>>(enc, Abf);
    gemm_scores_bf16<<<dim3(8, 512), 256, 0, stream>>>(Abf, Wt, ctx, bias, vw, attn);
    softmax_k<<<32, 256, 0, stream>>>(attn, mask);
    hipMemsetAsync(ctx, 0, (size_t)(BATCH * ENCD) * sizeof(float), stream);
    context_k<<<dim3(64, 32), 256, 0, stream>>>(attn, enc, ctx);
  } else {
    hipMemsetAsync(attn, 0, (size_t)MTOT * sizeof(float), stream);
    hipMemsetAsync(ctx, 0, (size_t)(BATCH * NDIM) * sizeof(float), stream);
    dec_proj_k2<<<dim3(128, 8), 256, 0, stream>>>(dec, W, ctx);
    gemm_scores_f32<<<dim3(8, 512), 256, 0, stream>>>(enc, Wt, ctx, bias, vw, attn);
    softmax_k<<<32, 256, 0, stream>>>(attn, mask);
    hipMemsetAsync(ctx, 0, (size_t)(BATCH * ENCD) * sizeof(float), stream);
    context_k<<<dim3(64, 32), 256, 0, stream>>>(attn, enc, ctx);
  }
}